// Round 2
// baseline (1275.163 us; speedup 1.0000x reference)
//
#include <hip/hip_runtime.h>
#include <math.h>

#define BATCH 32
#define TLEN 8192
#define NCH 128          // chunks
#define CLEN 64          // steps per chunk
#define SUBL 8           // steps per sub-chunk
#define NSUB 8           // sub-chunks per chunk
#define NROWS (BATCH*TLEN)   // 262144 rows

// ---------------------------------------------------------------------------
// HiPPO step: s <- (I - A/t) s + (x/t) * r
// (A s)[n] = (n+1)*s[n] + r[n] * sum_{m<n} r[m]*s[m]
// ---------------------------------------------------------------------------
__device__ __forceinline__ void hippo_step(float s[8], float inv_t, float xb) {
    const float R[8] = {1.0f, 1.7320508075688772f, 2.23606797749979f,
                        2.6457513110645907f, 3.0f, 3.3166247903554f,
                        3.605551275463989f, 3.872983346207417f};
    float p = 0.0f;
    #pragma unroll
    for (int n = 0; n < 8; n++) {
        float sn = s[n];
        float as = fmaf(R[n], p, (float)(n + 1) * sn);
        s[n] = fmaf(-inv_t, as, fmaf(xb, R[n], sn));
        p = fmaf(R[n], sn, p);
    }
}

// ---------------------------------------------------------------------------
// Kernel A: per-chunk runs. Threads 64..71 run unit-vector starts (P columns),
// threads 0..63 run zero starts with input (V). Every SUBL steps the running
// state is dumped -> sub-chunk transition data for the fine expand.
// ---------------------------------------------------------------------------
__global__ void hippo_chunk_kernel(const float* __restrict__ x_seq,
                                   float* __restrict__ Psub,  // [NCH][NSUB][8][8]
                                   float* __restrict__ Vsub,  // [NCH][NSUB][64][8]
                                   float* __restrict__ Pfin,  // [NCH][8][8]
                                   float* __restrict__ Vfin)  // [NCH][64][8]
{
    int chunk = blockIdx.x;
    int tid = threadIdx.x;
    if (tid >= 72) return;
    bool isP = tid >= 64;
    int col = tid - 64;
    int b = tid >> 1, c = tid & 1;

    float s[8];
    #pragma unroll
    for (int n = 0; n < 8; n++) s[n] = (isP && n == col) ? 1.0f : 0.0f;

    int t0 = chunk * CLEN;
    for (int i = 0; i < CLEN; i++) {
        if ((i & (SUBL - 1)) == 0) {
            int sub = i >> 3;
            if (isP) {
                #pragma unroll
                for (int n = 0; n < 8; n++)
                    Psub[(((size_t)chunk * NSUB + sub) * 8 + n) * 8 + col] = s[n];
            } else {
                #pragma unroll
                for (int n = 0; n < 8; n++)
                    Vsub[(((size_t)chunk * NSUB + sub) * 64 + tid) * 8 + n] = s[n];
            }
        }
        float tf = (float)(t0 + i + 1);
        float inv_t = 1.0f / tf;
        float x = 0.0f;
        if (!isP) x = x_seq[((size_t)(b * TLEN + t0 + i)) * 2 + c];
        hippo_step(s, inv_t, x * inv_t);
    }
    if (isP) {
        #pragma unroll
        for (int n = 0; n < 8; n++) Pfin[((size_t)chunk * 8 + n) * 8 + col] = s[n];
    } else {
        #pragma unroll
        for (int n = 0; n < 8; n++) Vfin[((size_t)chunk * 64 + tid) * 8 + n] = s[n];
    }
}

// ---------------------------------------------------------------------------
// Kernel B: sequential composition across chunks. One thread per (b,c).
// S0[chunk][seq] = state at the start of chunk.
// ---------------------------------------------------------------------------
__global__ void hippo_compose_kernel(const float* __restrict__ Pfin,
                                     const float* __restrict__ Vfin,
                                     float* __restrict__ S0)   // [NCH][64][8]
{
    int tid = threadIdx.x;   // 0..63
    float s[8];
    #pragma unroll
    for (int n = 0; n < 8; n++) s[n] = 0.0f;

    #pragma unroll 2
    for (int chunk = 0; chunk < NCH; chunk++) {
        #pragma unroll
        for (int n = 0; n < 8; n++) S0[((size_t)chunk * 64 + tid) * 8 + n] = s[n];
        float ns[8];
        #pragma unroll
        for (int n = 0; n < 8; n++) {
            float acc = Vfin[((size_t)chunk * 64 + tid) * 8 + n];
            #pragma unroll
            for (int m = 0; m < 8; m++)
                acc = fmaf(Pfin[((size_t)chunk * 8 + n) * 8 + m], s[m], acc);
            ns[n] = acc;
        }
        #pragma unroll
        for (int n = 0; n < 8; n++) s[n] = ns[n];
    }
}

// ---------------------------------------------------------------------------
// Kernel C: fine expand. One thread per (b, chunk, sub, c): matvec to the
// sub-chunk start state, then replay SUBL steps writing row-major
// h[row][16] (32B contiguous per step; c-pairs complete 64B lines).
// ---------------------------------------------------------------------------
__global__ __launch_bounds__(256) void hippo_expand_kernel(
    const float* __restrict__ x_seq,
    const float* __restrict__ Psub,
    const float* __restrict__ Vsub,
    const float* __restrict__ S0,
    float* __restrict__ h)               // [NROWS][16]
{
    int gid = blockIdx.x * 256 + threadIdx.x;   // 65536
    int c = gid & 1;
    int b = (gid >> 1) & 31;
    int sub = (gid >> 6) & 7;
    int chunk = gid >> 9;
    int seq = b * 2 + c;

    float s0v[8];
    #pragma unroll
    for (int n = 0; n < 8; n++)
        s0v[n] = S0[((size_t)chunk * 64 + seq) * 8 + n];

    const float* Pp = &Psub[((size_t)chunk * NSUB + sub) * 64];
    const float* Vp = &Vsub[(((size_t)chunk * NSUB + sub) * 64 + seq) * 8];

    float s[8];
    #pragma unroll
    for (int n = 0; n < 8; n++) {
        float acc = Vp[n];
        #pragma unroll
        for (int m = 0; m < 8; m++)
            acc = fmaf(Pp[n * 8 + m], s0v[m], acc);
        s[n] = acc;
    }

    int t0 = chunk * CLEN + sub * SUBL;
    #pragma unroll
    for (int i = 0; i < SUBL; i++) {
        int t = t0 + i;
        float tf = (float)(t + 1);
        float inv_t = 1.0f / tf;
        float x = x_seq[((size_t)(b * TLEN + t)) * 2 + c];
        hippo_step(s, inv_t, x * inv_t);
        float4* hp = (float4*)&h[((size_t)(b * TLEN + t)) * 16 + c * 8];
        hp[0] = make_float4(s[0], s[1], s[2], s[3]);
        hp[1] = make_float4(s[4], s[5], s[6], s[7]);
    }
}

// ---------------------------------------------------------------------------
// KAN: 4-nonzero-basis closed form for uniform cubic B-spline.
// ---------------------------------------------------------------------------
__device__ __forceinline__ void bspline4(float x, float& B0, float& B1,
                                         float& B2, float& B3, int& m)
{
    float tt = fmaf(x, 5.0f, 8.0f);        // (x + 1.6) * 5
    float fm = floorf(tt);
    float u = tt - fm;
    bool valid = (fm >= 0.0f) && (fm <= 15.0f);
    float u2 = u * u, u3 = u2 * u;
    float um = 1.0f - u;
    B0 = um * um * um * (1.0f / 6.0f);
    B3 = u3 * (1.0f / 6.0f);
    B1 = fmaf(3.0f, u3, fmaf(-6.0f, u2, 4.0f)) * (1.0f / 6.0f);
    B2 = fmaf(-3.0f, u3, fmaf(3.0f, u2, fmaf(3.0f, u, 1.0f))) * (1.0f / 6.0f);
    float msk = valid ? 1.0f : 0.0f;
    B0 *= msk; B1 *= msk; B2 *= msk; B3 *= msk;
    m = valid ? (int)fm : 0;
}

__device__ __forceinline__ float silu(float x) {
    return x / (1.0f + __expf(-x));
}

// All three layers fused, activations in registers (loops fully unrolled so
// activation arrays keep compile-time indices -> no scratch).
__global__ __launch_bounds__(256, 4) void kan_kernel(
    const float* __restrict__ h,         // [NROWS][16]
    const float* __restrict__ wb1, const float* __restrict__ ws1,
    const float* __restrict__ wb2, const float* __restrict__ ws2,
    const float* __restrict__ wb3, const float* __restrict__ ws3,
    float* __restrict__ out)
{
    __shared__ float wlds[10032];        // phase1: ws1p[32][304]; phase2: ws2p[16][608] + ws3p[304]
    int tid = threadIdx.x;
    int row = blockIdx.x * 256 + tid;

    // preload this row's 16 inputs (issues 4x dwordx4 before staging; vmcnt
    // drains under the LDS staging work)
    float x[16];
    {
        const float4* hp = (const float4*)(h + (size_t)row * 16);
        float4 a0 = hp[0], a1 = hp[1], a2 = hp[2], a3 = hp[3];
        x[0]=a0.x; x[1]=a0.y; x[2]=a0.z; x[3]=a0.w;
        x[4]=a1.x; x[5]=a1.y; x[6]=a1.z; x[7]=a1.w;
        x[8]=a2.x; x[9]=a2.y; x[10]=a2.z; x[11]=a2.w;
        x[12]=a3.x; x[13]=a3.y; x[14]=a3.z; x[15]=a3.w;
    }

    // ---- stage ws1 padded: wlds[o*304 + i*19 + 3 + j] = ws1[o][i*13+j]
    for (int idx = tid; idx < 9728; idx += 256) {
        int o = idx / 304;
        int k = idx - o * 304;
        int ii = k / 19;
        int jj = k - ii * 19 - 3;
        float v = 0.0f;
        if (jj >= 0 && jj < 13) v = ws1[o * 208 + ii * 13 + jj];
        wlds[idx] = v;
    }
    __syncthreads();

    // ---- layer 1: 16 -> 32
    float acc1[32];
    #pragma unroll
    for (int o = 0; o < 32; o++) acc1[o] = 0.0f;

    #pragma unroll
    for (int i = 0; i < 16; i++) {
        float xv = x[i];
        float sx = silu(xv);
        float B0, B1, B2, B3; int m;
        bspline4(xv, B0, B1, B2, B3, m);
        const float* wp = &wlds[i * 19 + m];
        #pragma unroll
        for (int o = 0; o < 32; o++) {
            float a = acc1[o];
            a = fmaf(sx, wb1[o * 16 + i], a);
            const float* w = wp + o * 304;
            a = fmaf(B0, w[0], a);
            a = fmaf(B1, w[1], a);
            a = fmaf(B2, w[2], a);
            a = fmaf(B3, w[3], a);
            acc1[o] = a;
        }
    }
    __syncthreads();   // done reading ws1

    // ---- stage ws2 + ws3 padded
    for (int idx = tid; idx < 10032; idx += 256) {
        float v = 0.0f;
        if (idx < 9728) {
            int o = idx / 608;
            int k = idx - o * 608;
            int ii = k / 19;
            int jj = k - ii * 19 - 3;
            if (jj >= 0 && jj < 13) v = ws2[o * 416 + ii * 13 + jj];
        } else {
            int k = idx - 9728;
            int ii = k / 19;
            int jj = k - ii * 19 - 3;
            if (jj >= 0 && jj < 13) v = ws3[ii * 13 + jj];
        }
        wlds[idx] = v;
    }
    __syncthreads();

    // ---- layer 2: 32 -> 16 (input = acc1 in registers)
    float acc2[16];
    #pragma unroll
    for (int o = 0; o < 16; o++) acc2[o] = 0.0f;

    #pragma unroll
    for (int i = 0; i < 32; i++) {
        float xv = acc1[i];
        float sx = silu(xv);
        float B0, B1, B2, B3; int m;
        bspline4(xv, B0, B1, B2, B3, m);
        const float* wp = &wlds[i * 19 + m];
        #pragma unroll
        for (int o = 0; o < 16; o++) {
            float a = acc2[o];
            a = fmaf(sx, wb2[o * 32 + i], a);
            const float* w = wp + o * 608;
            a = fmaf(B0, w[0], a);
            a = fmaf(B1, w[1], a);
            a = fmaf(B2, w[2], a);
            a = fmaf(B3, w[3], a);
            acc2[o] = a;
        }
    }

    // ---- layer 3: 16 -> 1 (input = acc2 in registers)
    float acc3 = 0.0f;
    #pragma unroll
    for (int i = 0; i < 16; i++) {
        float xv = acc2[i];
        float sx = silu(xv);
        float B0, B1, B2, B3; int m;
        bspline4(xv, B0, B1, B2, B3, m);
        const float* wp = &wlds[9728 + i * 19 + m];
        float a = acc3;
        a = fmaf(sx, wb3[i], a);
        a = fmaf(B0, wp[0], a);
        a = fmaf(B1, wp[1], a);
        a = fmaf(B2, wp[2], a);
        a = fmaf(B3, wp[3], a);
        acc3 = a;
    }
    out[row] = acc3;
}

// ---------------------------------------------------------------------------
extern "C" void kernel_launch(void* const* d_in, const int* in_sizes, int n_in,
                              void* d_out, int out_size, void* d_ws, size_t ws_size,
                              hipStream_t stream) {
    const float* x_seq = (const float*)d_in[0];
    const float* wb1   = (const float*)d_in[1];
    const float* ws1   = (const float*)d_in[2];
    const float* wb2   = (const float*)d_in[3];
    const float* ws2   = (const float*)d_in[4];
    const float* wb3   = (const float*)d_in[5];
    const float* ws3   = (const float*)d_in[6];

    float* ws   = (float*)d_ws;
    float* Psub = ws;                   // 128*8*64        =   65536
    float* Vsub = ws + 65536;           // 128*8*64*8      =  524288
    float* Pfin = ws + 589824;          // 128*64          =    8192
    float* Vfin = ws + 598016;          // 128*64*8        =   65536
    float* S0   = ws + 663552;          // 128*64*8        =   65536
    float* h    = ws + 729088;          // 262144*16       = 4194304
    float* out  = (float*)d_out;

    hipLaunchKernelGGL(hippo_chunk_kernel,   dim3(NCH), dim3(128), 0, stream,
                       x_seq, Psub, Vsub, Pfin, Vfin);
    hipLaunchKernelGGL(hippo_compose_kernel, dim3(1),   dim3(64),  0, stream,
                       Pfin, Vfin, S0);
    hipLaunchKernelGGL(hippo_expand_kernel,  dim3(256), dim3(256), 0, stream,
                       x_seq, Psub, Vsub, S0, h);
    hipLaunchKernelGGL(kan_kernel, dim3(NROWS / 256), dim3(256), 0, stream,
                       h, wb1, ws1, wb2, ws2, wb3, ws3, out);
}